// Round 1
// baseline (6786.048 us; speedup 1.0000x reference)
//
#include <hip/hip_runtime.h>
#include <math.h>

// Problem constants: B=64, N=512, R=E=1024, K_top=256
#define BR 65536L  // B*R

// ---------------- ws layout (float offsets) ----------------
#define E1_OFF   0L
#define E2_OFF   33554432L
#define ADJ_OFF  67108864L
#define SM_OFF   83886080L
#define GATES1_OFF (SM_OFF + 0L)
#define INPT_OFF   (SM_OFF + 262144L)
#define HATT_OFF   (SM_OFF + 524288L)
#define HATTT_OFF  (SM_OFF + 589824L)
#define V1_OFF     (SM_OFF + 655360L)
#define V2_OFF     (SM_OFF + 720896L)
#define PART_OFF   (SM_OFF + 786432L)
#define BMIN_OFF   (SM_OFF + 787456L)
#define ROWSUM_OFF (SM_OFF + 787520L)
#define DVEC_OFF   (SM_OFF + 820288L)
#define RS_OFF     (SM_OFF + 853056L)
#define PW0_OFF    (SM_OFF + 885824L)
#define ATTF_OFF   (SM_OFF + 951360L)
#define INP2T_OFF  (SM_OFF + 1016896L)
#define GATES2_OFF (SM_OFF + 1213504L)

// =====================================================================
// 128x128x8 fp32 tiled GEMM. BT: B is (N,K) row-major (C=A*B^T), else (K,N).
// EPI: 0 plain; 1 e-proj: C=mask[m]*(acc+colv[b,j])+bias[j];
//      2 gcn0: C=relu(acc+rowv[m]*colv[b,j]+bias[j])*mask[m];
//      3 gcn12: C=relu(acc+bias[j])*mask[m]
// =====================================================================
template<bool BT, int EPI>
__global__ __launch_bounds__(256) void gemm128(
    const float* __restrict__ A, const float* __restrict__ B, float* __restrict__ C,
    int M, int N, int K, int lda, int ldb, int ldc,
    long sA, long sB, long sC,
    const float* __restrict__ colv, const float* __restrict__ bias,
    const float* __restrict__ rowv, const float* __restrict__ maskrow)
{
    __shared__ float As[8][128];
    __shared__ float Bs[8][128];
    const int t  = threadIdx.x;
    const int m0 = blockIdx.y * 128;
    const int n0 = blockIdx.x * 128;
    const long zb = blockIdx.z;
    const float* Ab = A + zb * sA;
    const float* Bp = B + zb * sB;
    float* Cb = C + zb * sC;

    const int lm  = t >> 1;          // 0..127
    const int lk4 = (t & 1) * 4;     // 0 or 4
    const int lkb = t >> 5;          // 0..7   (NN B load)
    const int lnb = (t & 31) * 4;    // 0..124 (NN B load)
    const int tm  = t >> 4;          // 0..15
    const int tn  = t & 15;          // 0..15

    float acc[8][8];
#pragma unroll
    for (int i = 0; i < 8; ++i)
#pragma unroll
        for (int j = 0; j < 8; ++j) acc[i][j] = 0.f;

    for (int k0 = 0; k0 < K; k0 += 8) {
        const float4 av = *(const float4*)(Ab + (long)(m0 + lm) * lda + k0 + lk4);
        float4 bv;
        if (BT) bv = *(const float4*)(Bp + (long)(n0 + lm) * ldb + k0 + lk4);
        else    bv = *(const float4*)(Bp + (long)(k0 + lkb) * ldb + n0 + lnb);
        __syncthreads();   // previous tile fully consumed
        As[lk4 + 0][lm] = av.x;
        As[lk4 + 1][lm] = av.y;
        As[lk4 + 2][lm] = av.z;
        As[lk4 + 3][lm] = av.w;
        if (BT) {
            Bs[lk4 + 0][lm] = bv.x;
            Bs[lk4 + 1][lm] = bv.y;
            Bs[lk4 + 2][lm] = bv.z;
            Bs[lk4 + 3][lm] = bv.w;
        } else {
            *(float4*)(&Bs[lkb][lnb]) = bv;
        }
        __syncthreads();
#pragma unroll
        for (int kk = 0; kk < 8; ++kk) {
            float a[8], bb[8];
            *(float4*)(a)      = *(const float4*)(&As[kk][tm * 8]);
            *(float4*)(a + 4)  = *(const float4*)(&As[kk][tm * 8 + 4]);
            *(float4*)(bb)     = *(const float4*)(&Bs[kk][tn * 8]);
            *(float4*)(bb + 4) = *(const float4*)(&Bs[kk][tn * 8 + 4]);
#pragma unroll
            for (int i = 0; i < 8; ++i)
#pragma unroll
                for (int j = 0; j < 8; ++j)
                    acc[i][j] = fmaf(a[i], bb[j], acc[i][j]);
        }
    }

#pragma unroll
    for (int i = 0; i < 8; ++i) {
        const int m = m0 + tm * 8 + i;
        float* crow = Cb + (long)m * ldc + n0 + tn * 8;
        float o[8];
        if (EPI == 0) {
#pragma unroll
            for (int j = 0; j < 8; ++j) o[j] = acc[i][j];
        } else {
            const int bidx = m >> 9;       // row -> batch (N=512 rows/batch)
            const float mk = maskrow[m];
#pragma unroll
            for (int j = 0; j < 8; ++j) {
                const int n = n0 + tn * 8 + j;
                float v = acc[i][j];
                if (EPI == 1)      v = mk * (v + colv[bidx * 1024 + n]) + bias[n];
                else if (EPI == 2) v = fmaxf(v + rowv[m] * colv[bidx * 1024 + n] + bias[n], 0.f) * mk;
                else               v = fmaxf(v + bias[n], 0.f) * mk;
                o[j] = v;
            }
        }
        *(float4*)(crow)     = *(float4*)(o);
        *(float4*)(crow + 4) = *(float4*)(o + 4);
    }
}

// =====================================================================
// Small-M (M=64) NT GEMM: out[j,b] via lanes=b over transposed input.
// out[(long)j*sj + lane*sb] = sum_k inpT[k*64+b]*W1[j,k] (+W2 part) + biases
// =====================================================================
__global__ __launch_bounds__(256) void smallM_NT(
    const float* __restrict__ inpT,
    const float* __restrict__ W1, int K1, int ldw1,
    const float* __restrict__ W2, int K2, int ldw2,
    const float* __restrict__ b1, const float* __restrict__ b2,
    float* __restrict__ outp, int NJ, int sj, int sb)
{
    const int j = (blockIdx.x * blockDim.x + threadIdx.x) >> 6;
    const int lane = threadIdx.x & 63;
    if (j >= NJ) return;
    float acc = 0.f;
    const float* w = W1 + (long)j * ldw1;
    for (int k = 0; k < K1; k += 4) {
        const float4 wv = *(const float4*)(&w[k]);
        const float* ip = inpT + (long)k * 64 + lane;
        acc += wv.x * ip[0] + wv.y * ip[64] + wv.z * ip[128] + wv.w * ip[192];
    }
    if (W2) {
        const float* w2 = W2 + (long)j * ldw2;
        for (int k = 0; k < K2; k += 4) {
            const float4 wv = *(const float4*)(&w2[k]);
            const float* ip = inpT + (long)(K1 + k) * 64 + lane;
            acc += wv.x * ip[0] + wv.y * ip[64] + wv.z * ip[128] + wv.w * ip[192];
        }
    }
    float bias = 0.f;
    if (b1) bias += b1[j];
    if (b2) bias += b2[j];
    outp[(long)j * sj + (long)lane * sb] = acc + bias;
}

// Small-M NN GEMM: out[b*NJ + j] = sum_k A[b,k]*W[k,j]; lanes=j.
__global__ __launch_bounds__(256) void smallM_NN(
    const float* __restrict__ A, int lda,
    const float* __restrict__ W, int ldw, int K,
    float* __restrict__ outp, int NJ)
{
    const int wid = (blockIdx.x * blockDim.x + threadIdx.x) >> 6;
    const int lane = threadIdx.x & 63;
    const int nt = NJ >> 6;
    const int b = wid / nt;
    const int jt = wid - b * nt;
    if (b >= 64) return;
    const int j = jt * 64 + lane;
    float acc = 0.f;
    const float* a = A + (long)b * lda;
    for (int k = 0; k < K; k += 4) {
        const float a0 = a[k], a1 = a[k + 1], a2 = a[k + 2], a3 = a[k + 3];
        const float* wp = W + (long)k * ldw + j;
        acc += a0 * wp[0] + a1 * wp[ldw] + a2 * wp[2 * (long)ldw] + a3 * wp[3 * (long)ldw];
    }
    outp[(long)b * NJ + j] = acc;
}

// =====================================================================
// Packers (transposed small activations: [K][64] layout, b fastest)
// =====================================================================
__global__ void pack_inpT1(const float* __restrict__ xt, const float* __restrict__ fc,
                           const float* __restrict__ sh, float* __restrict__ inpT)
{
    const int idx = blockIdx.x * 256 + threadIdx.x;   // < 4096*64
    const int b = idx & 63;
    const int k = idx >> 6;
    float v;
    if (k < 1024)      v = sh[BR + b * 1024 + k];          // prev_h = state_h[1]
    else if (k < 2048) v = fc[b * 1024 + (k - 1024)];
    else if (k < 3072) v = xt[b * 1024 + (k - 2048)];
    else               v = sh[b * 1024 + (k - 3072)];      // h0 = state_h[0]
    inpT[idx] = v;
}

__global__ void pack_inp2T(const float* __restrict__ attf, const float* __restrict__ hatt,
                           const float* __restrict__ sh, float* __restrict__ inp2T)
{
    const int idx = blockIdx.x * 256 + threadIdx.x;   // < 3072*64
    const int b = idx & 63;
    const int k = idx >> 6;
    float v;
    if (k < 1024)      v = attf[b * 1024 + k];
    else if (k < 2048) v = hatt[b * 1024 + (k - 1024)];
    else               v = sh[BR + b * 1024 + (k - 2048)]; // prev_h
    inp2T[idx] = v;
}

// =====================================================================
// LSTM pointwise. gatesT layout [4096][64] (j-major), j = r / r+1024 / r+2048 / r+3072.
// =====================================================================
__global__ void lstm_pointwise(const float* __restrict__ gatesT, const float* __restrict__ cin,
                               float* __restrict__ hout, float* __restrict__ hT,
                               float* __restrict__ hout2, float* __restrict__ cout)
{
    const int idx = blockIdx.x * 256 + threadIdx.x;   // < 65536
    const int b = idx & 63;
    const int r = idx >> 6;
    const float ig = gatesT[(long)r * 64 + b];
    const float fg = gatesT[(long)(r + 1024) * 64 + b];
    const float gg = gatesT[(long)(r + 2048) * 64 + b];
    const float og = gatesT[(long)(r + 3072) * 64 + b];
    const float c0 = cin[b * 1024 + r];
    const float si = 1.f / (1.f + expf(-ig));
    const float sf = 1.f / (1.f + expf(-fg));
    const float so = 1.f / (1.f + expf(-og));
    const float cn = sf * c0 + si * tanhf(gg);
    const float hn = so * tanhf(cn);
    if (hout)  hout[b * 1024 + r] = hn;
    if (hT)    hT[(long)r * 64 + b] = hn;
    if (hout2) hout2[b * 1024 + r] = hn;
    if (cout)  cout[b * 1024 + r] = cn;
}

// =====================================================================
// Per-batch min of raw Adj
// =====================================================================
__global__ void min_partial(const float* __restrict__ Adj, float* __restrict__ part)
{
    const int b = blockIdx.y;
    const float* p = Adj + (long)b * 262144 + (long)blockIdx.x * 16384;
    float m = INFINITY;
    for (int i = threadIdx.x; i < 16384; i += 256) m = fminf(m, p[i]);
    __shared__ float red[256];
    red[threadIdx.x] = m;
    __syncthreads();
    for (int o = 128; o; o >>= 1) {
        if (threadIdx.x < o) red[threadIdx.x] = fminf(red[threadIdx.x], red[threadIdx.x + o]);
        __syncthreads();
    }
    if (threadIdx.x == 0) part[b * 16 + blockIdx.x] = red[0];
}

__global__ void min_final(const float* __restrict__ part, float* __restrict__ bmin)
{
    const int b = threadIdx.x;
    if (b < 64) {
        float m = INFINITY;
        for (int i = 0; i < 16; ++i) m = fminf(m, part[b * 16 + i]);
        bmin[b] = m;
    }
}

// =====================================================================
// Per-row exact top-K (K=256) with jax.lax.top_k tie semantics
// (stable: lower indices win among equal values). One wave per row.
// Applies (v - bmin)*rowmask first, zeroes non-kept, emits rowsum.
// =====================================================================
__global__ __launch_bounds__(256) void topk_rows(float* __restrict__ Adj,
                                                 const float* __restrict__ bmin,
                                                 const float* __restrict__ mask,
                                                 float* __restrict__ rowsum)
{
    const int wid = (blockIdx.x * 256 + threadIdx.x) >> 6;   // row 0..32767
    const int lane = threadIdx.x & 63;
    const int b = wid >> 9;
    float* row = Adj + (long)wid * 512;
    const float bm = bmin[b];
    const float rmask = mask[wid];

    float v[8];
    unsigned u[8];
#pragma unroll
    for (int i = 0; i < 8; ++i) {
        const float x = (row[i * 64 + lane] - bm) * rmask;   // >= 0
        v[i] = x;
        u[i] = __float_as_uint(x);
    }
    // binary search for K-th largest bit pattern (values non-negative => monotonic)
    unsigned lo = 0u, hi = 0x80000000u;
    while (hi - lo > 1u) {
        const unsigned mid = lo + ((hi - lo) >> 1);
        int c = 0;
#pragma unroll
        for (int i = 0; i < 8; ++i) c += __popcll(__ballot(u[i] >= mid));
        if (c >= 256) lo = mid; else hi = mid;
    }
    const unsigned thr = lo;
    unsigned long long beq[8];
    int cnt_gt = 0;
#pragma unroll
    for (int i = 0; i < 8; ++i) {
        cnt_gt += __popcll(__ballot(u[i] > thr));
        beq[i] = __ballot(u[i] == thr);
    }
    const int need = 256 - cnt_gt;
    int cum = 0;
    float s = 0.f;
    const unsigned long long lmask = (lane == 63) ? 0x7FFFFFFFFFFFFFFFull
                                                  : ((1ull << lane) - 1ull);
#pragma unroll
    for (int i = 0; i < 8; ++i) {
        const int rank = cum + __popcll(beq[i] & lmask);
        const bool keep = (u[i] > thr) || ((u[i] == thr) && (rank < need));
        const float ov = keep ? v[i] : 0.f;
        row[i * 64 + lane] = ov;
        s += ov;
        cum += __popcll(beq[i]);
    }
    for (int off = 32; off; off >>= 1) s += __shfl_down(s, off);
    if (lane == 0) rowsum[wid] = s;
}

__global__ void dvec_kernel(const float* __restrict__ rowsum, float* __restrict__ dv)
{
    const int r = blockIdx.x * 256 + threadIdx.x;
    if (r < 32768) {
        const float s = rowsum[r];
        dv[r] = (s > 0.f) ? (1.f / sqrtf(s)) : 0.f;
    }
}

// Adj[r][m] *= d[r]*d[b,m]*colmask[b,m]; rs[r] = row sum of result
__global__ void adj_norm(float* __restrict__ Adj, const float* __restrict__ dv,
                         const float* __restrict__ mask, float* __restrict__ rs)
{
    const int r = blockIdx.x;
    const int b = r >> 9;
    const float dn = dv[r];
    float* row = Adj + (long)r * 512;
    float s = 0.f;
    for (int m = threadIdx.x; m < 512; m += 256) {
        const float val = row[m] * dn * dv[b * 512 + m] * mask[b * 512 + m];
        row[m] = val;
        s += val;
    }
    __shared__ float red[256];
    red[threadIdx.x] = s;
    __syncthreads();
    for (int o = 128; o; o >>= 1) {
        if (threadIdx.x < o) red[threadIdx.x] += red[threadIdx.x + o];
        __syncthreads();
    }
    if (threadIdx.x == 0) rs[r] = red[0];
}

// att[b][j] = max_n x[b][n][j]
__global__ void colmax_kernel(const float* __restrict__ x, float* __restrict__ att)
{
    const int j = blockIdx.x * 256 + threadIdx.x;
    const int b = blockIdx.y;
    const float* p = x + (long)b * 524288 + j;
    float m = -INFINITY;
#pragma unroll 4
    for (int n = 0; n < 512; ++n) m = fmaxf(m, p[(long)n * 1024]);
    att[b * 1024 + j] = m;
}

// =====================================================================
extern "C" void kernel_launch(void* const* d_in, const int* in_sizes, int n_in,
                              void* d_out, int out_size, void* d_ws, size_t ws_size,
                              hipStream_t stream)
{
    const float* xt   = (const float*)d_in[0];
    const float* fc   = (const float*)d_in[1];
    const float* ge   = (const float*)d_in[2];
    const float* sh   = (const float*)d_in[4];   // state_h (2,B,R)
    const float* sc   = (const float*)d_in[5];   // state_c (2,B,R)
    const float* mask = (const float*)d_in[6];   // att_mask (B,N)
    const float* aWih = (const float*)d_in[7];
    const float* aWhh = (const float*)d_in[8];
    const float* aBih = (const float*)d_in[9];
    const float* aBhh = (const float*)d_in[10];
    const float* lWih = (const float*)d_in[11];
    const float* lWhh = (const float*)d_in[12];
    const float* lBih = (const float*)d_in[13];
    const float* lBhh = (const float*)d_in[14];
    const float* e1W  = (const float*)d_in[15];
    const float* e1b  = (const float*)d_in[16];
    const float* e2W  = (const float*)d_in[17];
    const float* e2b  = (const float*)d_in[18];
    const float* W0   = (const float*)d_in[19];
    const float* b0   = (const float*)d_in[20];
    const float* W1   = (const float*)d_in[21];
    const float* b1   = (const float*)d_in[22];
    const float* W2   = (const float*)d_in[23];
    const float* b2   = (const float*)d_in[24];

    float* out = (float*)d_out;
    float* ws  = (float*)d_ws;

    float* e1      = ws + E1_OFF;
    float* e2      = ws + E2_OFF;
    float* Adj     = ws + ADJ_OFF;
    float* tbuf    = e1;   // reuse after Adj is final
    float* xbuf    = e2;   // reuse after Adj is final
    float* gatesT  = ws + GATES1_OFF;
    float* inpT    = ws + INPT_OFF;
    float* h_att   = ws + HATT_OFF;
    float* h_attT  = ws + HATTT_OFF;
    float* v1      = ws + V1_OFF;
    float* v2      = ws + V2_OFF;
    float* part    = ws + PART_OFF;
    float* bmin    = ws + BMIN_OFF;
    float* rowsum  = ws + ROWSUM_OFF;
    float* dv      = ws + DVEC_OFF;
    float* rs      = ws + RS_OFF;
    float* pw0     = ws + PW0_OFF;
    float* attf    = ws + ATTF_OFF;
    float* inp2T   = ws + INP2T_OFF;
    float* gates2T = ws + GATES2_OFF;

    // ---- attention LSTM ----
    pack_inpT1<<<1024, 256, 0, stream>>>(xt, fc, sh, inpT);
    smallM_NT<<<1024, 256, 0, stream>>>(inpT, aWih, 3072, 3072, aWhh, 1024, 1024,
                                        aBih, aBhh, gatesT, 4096, 64, 1);
    lstm_pointwise<<<256, 256, 0, stream>>>(gatesT, sc, h_att, h_attT,
                                            out + BR, out + 3 * BR);

    // ---- e1/e2 bias vectors from h_att ----
    smallM_NT<<<256, 256, 0, stream>>>(h_attT, e1W + 1024, 1024, 2048,
                                       nullptr, 0, 0, nullptr, nullptr, v1, 1024, 1, 1024);
    smallM_NT<<<256, 256, 0, stream>>>(h_attT, e2W + 1024, 1024, 2048,
                                       nullptr, 0, 0, nullptr, nullptr, v2, 1024, 1, 1024);

    // ---- e1, e2 projections (NT, epi1) ----
    gemm128<true, 1><<<dim3(8, 256, 1), 256, 0, stream>>>(
        ge, e1W, e1, 32768, 1024, 1024, 1024, 2048, 1024, 0, 0, 0, v1, e1b, nullptr, mask);
    gemm128<true, 1><<<dim3(8, 256, 1), 256, 0, stream>>>(
        ge, e2W, e2, 32768, 1024, 1024, 1024, 2048, 1024, 0, 0, 0, v2, e2b, nullptr, mask);

    // ---- Adj = e1 @ e2^T (batched NT) ----
    gemm128<true, 0><<<dim3(4, 4, 64), 256, 0, stream>>>(
        e1, e2, Adj, 512, 512, 1024, 1024, 1024, 512,
        524288, 524288, 262144, nullptr, nullptr, nullptr, nullptr);

    // ---- min / top-k / normalization ----
    min_partial<<<dim3(16, 64), 256, 0, stream>>>(Adj, part);
    min_final<<<1, 64, 0, stream>>>(part, bmin);
    topk_rows<<<8192, 256, 0, stream>>>(Adj, bmin, mask, rowsum);
    dvec_kernel<<<128, 256, 0, stream>>>(rowsum, dv);
    adj_norm<<<32768, 256, 0, stream>>>(Adj, dv, mask, rs);

    // ---- GCN layer 0 (rank-1 trick for prev_h part) ----
    smallM_NN<<<256, 256, 0, stream>>>(sh + BR, 1024, W0 + 1024 * 1024, 1024, 1024, pw0, 1024);
    gemm128<false, 0><<<dim3(8, 4, 64), 256, 0, stream>>>(
        Adj, ge, tbuf, 512, 1024, 512, 512, 1024, 1024,
        262144, 524288, 524288, nullptr, nullptr, nullptr, nullptr);
    gemm128<false, 2><<<dim3(8, 256, 1), 256, 0, stream>>>(
        tbuf, W0, xbuf, 32768, 1024, 1024, 1024, 1024, 1024, 0, 0, 0, pw0, b0, rs, mask);

    // ---- GCN layer 1 ----
    gemm128<false, 0><<<dim3(8, 4, 64), 256, 0, stream>>>(
        Adj, xbuf, tbuf, 512, 1024, 512, 512, 1024, 1024,
        262144, 524288, 524288, nullptr, nullptr, nullptr, nullptr);
    gemm128<false, 3><<<dim3(8, 256, 1), 256, 0, stream>>>(
        tbuf, W1, xbuf, 32768, 1024, 1024, 1024, 1024, 1024, 0, 0, 0, nullptr, b1, nullptr, mask);

    // ---- GCN layer 2 ----
    gemm128<false, 0><<<dim3(8, 4, 64), 256, 0, stream>>>(
        Adj, xbuf, tbuf, 512, 1024, 512, 512, 1024, 1024,
        262144, 524288, 524288, nullptr, nullptr, nullptr, nullptr);
    gemm128<false, 3><<<dim3(8, 256, 1), 256, 0, stream>>>(
        tbuf, W2, xbuf, 32768, 1024, 1024, 1024, 1024, 1024, 0, 0, 0, nullptr, b2, nullptr, mask);

    // ---- column max over N ----
    colmax_kernel<<<dim3(4, 64), 256, 0, stream>>>(xbuf, attf);

    // ---- language LSTM ----
    pack_inp2T<<<768, 256, 0, stream>>>(attf, h_att, sh, inp2T);
    smallM_NT<<<1024, 256, 0, stream>>>(inp2T, lWih, 2048, 2048, lWhh, 1024, 1024,
                                        lBih, lBhh, gates2T, 4096, 64, 1);
    lstm_pointwise<<<256, 256, 0, stream>>>(gates2T, sc + BR, out, nullptr,
                                            out + 2 * BR, out + 4 * BR);
    (void)in_sizes; (void)n_in; (void)out_size; (void)ws_size;
}

// Round 3
// 3654.609 us; speedup vs baseline: 1.8568x; 1.8568x over previous
//
#include <hip/hip_runtime.h>
#include <math.h>

// Problem constants: B=64, N=512, R=E=1024, K_top=256
#define BR 65536L  // B*R

// ---------------- ws layout (float offsets) — round-1 proven ----------------
#define E1_OFF   0L
#define E2_OFF   33554432L
#define ADJ_OFF  67108864L
#define SM_OFF   83886080L
#define GATES1_OFF (SM_OFF + 0L)
#define INPT_OFF   (SM_OFF + 262144L)
#define HATT_OFF   (SM_OFF + 524288L)
#define HATTT_OFF  (SM_OFF + 589824L)
#define V1_OFF     (SM_OFF + 655360L)
#define V2_OFF     (SM_OFF + 720896L)
#define PART_OFF   (SM_OFF + 786432L)
#define BMIN_OFF   (SM_OFF + 787456L)
#define ROWSUM_OFF (SM_OFF + 787520L)
#define DVEC_OFF   (SM_OFF + 820288L)
#define RS_OFF     (SM_OFF + 853056L)
#define PW0_OFF    (SM_OFF + 885824L)
#define ATTF_OFF   (SM_OFF + 951360L)
#define INP2T_OFF  (SM_OFF + 1016896L)
#define GATES2_OFF (SM_OFF + 1213504L)

typedef unsigned short ushort_t;
typedef __attribute__((ext_vector_type(4))) float f32x4;
typedef __attribute__((ext_vector_type(8))) short bf16x8;

__device__ __forceinline__ ushort_t f2bf(float f) {
    unsigned u = __float_as_uint(f);
    unsigned r = u + 0x7FFFu + ((u >> 16) & 1u);
    return (ushort_t)(r >> 16);
}
__device__ __forceinline__ float bf2f(ushort_t h) {
    return __uint_as_float((unsigned)h << 16);
}
__device__ __forceinline__ void split2(float v, ushort_t& h, ushort_t& l) {
    h = f2bf(v);
    l = f2bf(v - bf2f(h));
}

// =====================================================================
// Split-bf16 MFMA GEMM with fp32 interface (drop-in for round-1 gemm128).
// C = A @ op(B), op = B^T if BT (B is N x K row-major) else B (K x N).
// Internally: per 128x128x32 step, fp32 tiles are reg-staged, split into
// hi/lo bf16, written to LDS [kq(4)][row(128)][8], and accumulated with
// 3-pass mfma_f32_16x16x32_bf16 (Ah*Bh + Ah*Bl + Al*Bh) in fp32 AGPRs.
// Split representation error ~2^-17 relative: fp32-class end to end.
// EPI: 0 plain fp32 C; 1 e-proj: C=mask[m]*(acc+colv[b,j])+bias[j];
//      2 gcn0: relu(acc+rowv[m]*colv[b,j]+bias[j])*mask[m];
//      3 gcn12: relu(acc+bias[j])*mask[m]
// =====================================================================
template<bool BT, int EPI>
__global__ __launch_bounds__(256) void gemm_mfma(
    const float* __restrict__ A, const float* __restrict__ B, float* __restrict__ C,
    int M, int N, int K, int lda, int ldb, int ldc,
    long sA, long sB, long sC,
    const float* __restrict__ colv, const float* __restrict__ bias,
    const float* __restrict__ rowv, const float* __restrict__ maskrow)
{
    // ushort units: Ah@0, Al@4096, Bh@8192, Bl@12288  (each [4][128][8])
    __shared__ __align__(16) ushort_t sm[16384];
    const int tid = threadIdx.x;
    const int w = tid >> 6, lane = tid & 63;
    const int m0 = blockIdx.y << 7, n0 = blockIdx.x << 7;
    const long zb = blockIdx.z;
    const float* Ab = A + zb * sA;
    const float* Bb = B + zb * sB;

    // row-style staging (A always; B when BT): row = tid>>1, khalf = tid&1
    const int srow = tid >> 1, skh = tid & 1;
    // NN B staging: kr = tid>>3 (0..31), ng = tid&7
    const int skr = tid >> 3, sng = tid & 7;

    // fragment indices
    const int lr = lane & 15, fq = lane >> 4;
    const int wm = (w >> 1) << 6, wn = (w & 1) << 6;
    const int aoff = (fq << 10) + ((wm + lr) << 3);          // ushort units
    const int boff = 8192 + (fq << 10) + ((wn + lr) << 3);

    f32x4 acc[4][4];
#pragma unroll
    for (int i = 0; i < 4; ++i)
#pragma unroll
        for (int j = 0; j < 4; ++j) acc[i][j] = (f32x4){0.f, 0.f, 0.f, 0.f};

    for (int k0 = 0; k0 < K; k0 += 32) {
        // ---- global loads to registers (touch no LDS; overlap prior compute)
        float4 a4[4], b4[4];
        {
            const float* ap = Ab + (long)(m0 + srow) * lda + k0 + skh * 16;
#pragma unroll
            for (int q = 0; q < 4; ++q) a4[q] = *(const float4*)(ap + q * 4);
        }
        if (BT) {
            const float* bp = Bb + (long)(n0 + srow) * ldb + k0 + skh * 16;
#pragma unroll
            for (int q = 0; q < 4; ++q) b4[q] = *(const float4*)(bp + q * 4);
        } else {
            const float* bp = Bb + (long)(k0 + skr) * ldb + n0 + sng * 16;
#pragma unroll
            for (int q = 0; q < 4; ++q) b4[q] = *(const float4*)(bp + q * 4);
        }
        __syncthreads();   // previous iteration's LDS reads complete

        // ---- split + LDS writes
        {
            ushort_t hs[16], ls[16];
#pragma unroll
            for (int q = 0; q < 4; ++q) {
                const float vv[4] = {a4[q].x, a4[q].y, a4[q].z, a4[q].w};
#pragma unroll
                for (int e = 0; e < 4; ++e) split2(vv[e], hs[q * 4 + e], ls[q * 4 + e]);
            }
            const int kq0 = skh << 1;
            ushort_t* hd = sm + (kq0 << 10) + (srow << 3);
            ushort_t* ld = hd + 4096;
            *(bf16x8*)(hd)        = *(bf16x8*)(hs);
            *(bf16x8*)(hd + 1024) = *(bf16x8*)(hs + 8);
            *(bf16x8*)(ld)        = *(bf16x8*)(ls);
            *(bf16x8*)(ld + 1024) = *(bf16x8*)(ls + 8);
        }
        if (BT) {
            ushort_t hs[16], ls[16];
#pragma unroll
            for (int q = 0; q < 4; ++q) {
                const float vv[4] = {b4[q].x, b4[q].y, b4[q].z, b4[q].w};
#pragma unroll
                for (int e = 0; e < 4; ++e) split2(vv[e], hs[q * 4 + e], ls[q * 4 + e]);
            }
            const int kq0 = skh << 1;
            ushort_t* hd = sm + 8192 + (kq0 << 10) + (srow << 3);
            ushort_t* ld = hd + 4096;
            *(bf16x8*)(hd)        = *(bf16x8*)(hs);
            *(bf16x8*)(hd + 1024) = *(bf16x8*)(hs + 8);
            *(bf16x8*)(ld)        = *(bf16x8*)(ls);
            *(bf16x8*)(ld + 1024) = *(bf16x8*)(ls + 8);
        } else {
            const int kq = skr >> 3, ke = skr & 7;
            ushort_t* hbase = sm + 8192  + (kq << 10) + ke;
            ushort_t* lbase = sm + 12288 + (kq << 10) + ke;
#pragma unroll
            for (int q = 0; q < 4; ++q) {
                const float vv[4] = {b4[q].x, b4[q].y, b4[q].z, b4[q].w};
#pragma unroll
                for (int e = 0; e < 4; ++e) {
                    ushort_t h, l; split2(vv[e], h, l);
                    const int c = sng * 16 + q * 4 + e;
                    hbase[c << 3] = h;
                    lbase[c << 3] = l;
                }
            }
        }
        __syncthreads();   // writes visible to all waves

        // ---- fragments + 3-pass MFMA
        bf16x8 ah4[4], al4[4];
#pragma unroll
        for (int mf = 0; mf < 4; ++mf) {
            ah4[mf] = *(const bf16x8*)(sm + aoff + (mf << 7));
            al4[mf] = *(const bf16x8*)(sm + 4096 + aoff + (mf << 7));
        }
#pragma unroll
        for (int nf = 0; nf < 4; ++nf) {
            const bf16x8 bh8 = *(const bf16x8*)(sm + boff + (nf << 7));
            const bf16x8 bl8 = *(const bf16x8*)(sm + 4096 + boff + (nf << 7));
#pragma unroll
            for (int mf = 0; mf < 4; ++mf) {
                acc[mf][nf] = __builtin_amdgcn_mfma_f32_16x16x32_bf16(ah4[mf], bh8, acc[mf][nf], 0, 0, 0);
                acc[mf][nf] = __builtin_amdgcn_mfma_f32_16x16x32_bf16(ah4[mf], bl8, acc[mf][nf], 0, 0, 0);
                acc[mf][nf] = __builtin_amdgcn_mfma_f32_16x16x32_bf16(al4[mf], bh8, acc[mf][nf], 0, 0, 0);
            }
        }
    }

    // ---- epilogue: D row = m0+wm+fq*4+mf*16+r, col = n0+wn+lr+nf*16
#pragma unroll
    for (int mf = 0; mf < 4; ++mf) {
#pragma unroll
        for (int nf = 0; nf < 4; ++nf) {
            const int m_b = m0 + wm + (fq << 2) + (mf << 4);
            const int n_g = n0 + wn + lr + (nf << 4);
            float* cp = C + zb * sC + (long)m_b * ldc + n_g;
            if (EPI == 0) {
#pragma unroll
                for (int r = 0; r < 4; ++r) cp[(long)r * ldc] = acc[mf][nf][r];
            } else {
                const int bidx = m_b >> 9;
                const float cv = (EPI <= 2) ? colv[(bidx << 10) + n_g] : 0.f;
                const float bi = bias[n_g];
#pragma unroll
                for (int r = 0; r < 4; ++r) {
                    const int m_g = m_b + r;
                    const float mk = maskrow[m_g];
                    float v = acc[mf][nf][r];
                    if (EPI == 1)      v = mk * (v + cv) + bi;
                    else if (EPI == 2) v = fmaxf(v + rowv[m_g] * cv + bi, 0.f) * mk;
                    else               v = fmaxf(v + bi, 0.f) * mk;
                    cp[(long)r * ldc] = v;
                }
            }
        }
    }
    (void)M; (void)N;
}

// =====================================================================
// Small-M (M=64) NT GEMM: out[j,b] via lanes=b over transposed input.
// =====================================================================
__global__ __launch_bounds__(256) void smallM_NT(
    const float* __restrict__ inpT,
    const float* __restrict__ W1, int K1, int ldw1,
    const float* __restrict__ W2, int K2, int ldw2,
    const float* __restrict__ b1, const float* __restrict__ b2,
    float* __restrict__ outp, int NJ, int sj, int sb)
{
    const int j = (blockIdx.x * blockDim.x + threadIdx.x) >> 6;
    const int lane = threadIdx.x & 63;
    if (j >= NJ) return;
    float acc = 0.f;
    const float* w = W1 + (long)j * ldw1;
    for (int k = 0; k < K1; k += 4) {
        const float4 wv = *(const float4*)(&w[k]);
        const float* ip = inpT + (long)k * 64 + lane;
        acc += wv.x * ip[0] + wv.y * ip[64] + wv.z * ip[128] + wv.w * ip[192];
    }
    if (W2) {
        const float* w2 = W2 + (long)j * ldw2;
        for (int k = 0; k < K2; k += 4) {
            const float4 wv = *(const float4*)(&w2[k]);
            const float* ip = inpT + (long)(K1 + k) * 64 + lane;
            acc += wv.x * ip[0] + wv.y * ip[64] + wv.z * ip[128] + wv.w * ip[192];
        }
    }
    float bias = 0.f;
    if (b1) bias += b1[j];
    if (b2) bias += b2[j];
    outp[(long)j * sj + (long)lane * sb] = acc + bias;
}

// Small-M NN GEMM: out[b*NJ + j] = sum_k A[b,k]*W[k,j]; lanes=j.
__global__ __launch_bounds__(256) void smallM_NN(
    const float* __restrict__ A, int lda,
    const float* __restrict__ W, int ldw, int K,
    float* __restrict__ outp, int NJ)
{
    const int wid = (blockIdx.x * blockDim.x + threadIdx.x) >> 6;
    const int lane = threadIdx.x & 63;
    const int nt = NJ >> 6;
    const int b = wid / nt;
    const int jt = wid - b * nt;
    if (b >= 64) return;
    const int j = jt * 64 + lane;
    float acc = 0.f;
    const float* a = A + (long)b * lda;
    for (int k = 0; k < K; k += 4) {
        const float a0 = a[k], a1 = a[k + 1], a2 = a[k + 2], a3 = a[k + 3];
        const float* wp = W + (long)k * ldw + j;
        acc += a0 * wp[0] + a1 * wp[ldw] + a2 * wp[2 * (long)ldw] + a3 * wp[3 * (long)ldw];
    }
    outp[(long)b * NJ + j] = acc;
}

// =====================================================================
// Packers (transposed small activations: [K][64] layout, b fastest)
// =====================================================================
__global__ void pack_inpT1(const float* __restrict__ xt, const float* __restrict__ fc,
                           const float* __restrict__ sh, float* __restrict__ inpT)
{
    const int idx = blockIdx.x * 256 + threadIdx.x;   // < 4096*64
    const int b = idx & 63;
    const int k = idx >> 6;
    float v;
    if (k < 1024)      v = sh[BR + b * 1024 + k];          // prev_h = state_h[1]
    else if (k < 2048) v = fc[b * 1024 + (k - 1024)];
    else if (k < 3072) v = xt[b * 1024 + (k - 2048)];
    else               v = sh[b * 1024 + (k - 3072)];      // h0 = state_h[0]
    inpT[idx] = v;
}

__global__ void pack_inp2T(const float* __restrict__ attf, const float* __restrict__ hatt,
                           const float* __restrict__ sh, float* __restrict__ inp2T)
{
    const int idx = blockIdx.x * 256 + threadIdx.x;   // < 3072*64
    const int b = idx & 63;
    const int k = idx >> 6;
    float v;
    if (k < 1024)      v = attf[b * 1024 + k];
    else if (k < 2048) v = hatt[b * 1024 + (k - 1024)];
    else               v = sh[BR + b * 1024 + (k - 2048)]; // prev_h
    inp2T[idx] = v;
}

// =====================================================================
// LSTM pointwise. gatesT layout [4096][64] (j-major).
// =====================================================================
__global__ void lstm_pointwise(const float* __restrict__ gatesT, const float* __restrict__ cin,
                               float* __restrict__ hout, float* __restrict__ hT,
                               float* __restrict__ hout2, float* __restrict__ cout)
{
    const int idx = blockIdx.x * 256 + threadIdx.x;   // < 65536
    const int b = idx & 63;
    const int r = idx >> 6;
    const float ig = gatesT[(long)r * 64 + b];
    const float fg = gatesT[(long)(r + 1024) * 64 + b];
    const float gg = gatesT[(long)(r + 2048) * 64 + b];
    const float og = gatesT[(long)(r + 3072) * 64 + b];
    const float c0 = cin[b * 1024 + r];
    const float si = 1.f / (1.f + expf(-ig));
    const float sf = 1.f / (1.f + expf(-fg));
    const float so = 1.f / (1.f + expf(-og));
    const float cn = sf * c0 + si * tanhf(gg);
    const float hn = so * tanhf(cn);
    if (hout)  hout[b * 1024 + r] = hn;
    if (hT)    hT[(long)r * 64 + b] = hn;
    if (hout2) hout2[b * 1024 + r] = hn;
    if (cout)  cout[b * 1024 + r] = cn;
}

// =====================================================================
// Per-batch min of raw Adj
// =====================================================================
__global__ void min_partial(const float* __restrict__ Adj, float* __restrict__ part)
{
    const int b = blockIdx.y;
    const float* p = Adj + (long)b * 262144 + (long)blockIdx.x * 16384;
    float m = INFINITY;
    for (int i = threadIdx.x; i < 16384; i += 256) m = fminf(m, p[i]);
    __shared__ float red[256];
    red[threadIdx.x] = m;
    __syncthreads();
    for (int o = 128; o; o >>= 1) {
        if (threadIdx.x < o) red[threadIdx.x] = fminf(red[threadIdx.x], red[threadIdx.x + o]);
        __syncthreads();
    }
    if (threadIdx.x == 0) part[b * 16 + blockIdx.x] = red[0];
}

__global__ void min_final(const float* __restrict__ part, float* __restrict__ bmin)
{
    const int b = threadIdx.x;
    if (b < 64) {
        float m = INFINITY;
        for (int i = 0; i < 16; ++i) m = fminf(m, part[b * 16 + i]);
        bmin[b] = m;
    }
}

// =====================================================================
// Per-row exact top-K (K=256), jax.lax.top_k tie semantics. One wave/row.
// =====================================================================
__global__ __launch_bounds__(256) void topk_rows(float* __restrict__ Adj,
                                                 const float* __restrict__ bmin,
                                                 const float* __restrict__ mask,
                                                 float* __restrict__ rowsum)
{
    const int wid = (blockIdx.x * 256 + threadIdx.x) >> 6;   // row 0..32767
    const int lane = threadIdx.x & 63;
    const int b = wid >> 9;
    float* row = Adj + (long)wid * 512;
    const float bm = bmin[b];
    const float rmask = mask[wid];

    float v[8];
    unsigned u[8];
#pragma unroll
    for (int i = 0; i < 8; ++i) {
        const float x = (row[i * 64 + lane] - bm) * rmask;   // >= 0
        v[i] = x;
        u[i] = __float_as_uint(x);
    }
    unsigned lo = 0u, hi = 0x80000000u;
    while (hi - lo > 1u) {
        const unsigned mid = lo + ((hi - lo) >> 1);
        int c = 0;
#pragma unroll
        for (int i = 0; i < 8; ++i) c += __popcll(__ballot(u[i] >= mid));
        if (c >= 256) lo = mid; else hi = mid;
    }
    const unsigned thr = lo;
    unsigned long long beq[8];
    int cnt_gt = 0;
#pragma unroll
    for (int i = 0; i < 8; ++i) {
        cnt_gt += __popcll(__ballot(u[i] > thr));
        beq[i] = __ballot(u[i] == thr);
    }
    const int need = 256 - cnt_gt;
    int cum = 0;
    float s = 0.f;
    const unsigned long long lmask = (lane == 63) ? 0x7FFFFFFFFFFFFFFFull
                                                  : ((1ull << lane) - 1ull);
#pragma unroll
    for (int i = 0; i < 8; ++i) {
        const int rank = cum + __popcll(beq[i] & lmask);
        const bool keep = (u[i] > thr) || ((u[i] == thr) && (rank < need));
        const float ov = keep ? v[i] : 0.f;
        row[i * 64 + lane] = ov;
        s += ov;
        cum += __popcll(beq[i]);
    }
    for (int off = 32; off; off >>= 1) s += __shfl_down(s, off);
    if (lane == 0) rowsum[wid] = s;
}

__global__ void dvec_kernel(const float* __restrict__ rowsum, float* __restrict__ dv)
{
    const int r = blockIdx.x * 256 + threadIdx.x;
    if (r < 32768) {
        const float s = rowsum[r];
        dv[r] = (s > 0.f) ? (1.f / sqrtf(s)) : 0.f;
    }
}

// Adj[r][m] *= d[r]*d[b,m]*colmask[b,m]; rs[r] = row sum of result
__global__ void adj_norm(float* __restrict__ Adj, const float* __restrict__ dv,
                         const float* __restrict__ mask, float* __restrict__ rs)
{
    const int r = blockIdx.x;
    const int b = r >> 9;
    const float dn = dv[r];
    float* row = Adj + (long)r * 512;
    float s = 0.f;
    for (int m = threadIdx.x; m < 512; m += 256) {
        const float val = row[m] * dn * dv[b * 512 + m] * mask[b * 512 + m];
        row[m] = val;
        s += val;
    }
    __shared__ float red[256];
    red[threadIdx.x] = s;
    __syncthreads();
    for (int o = 128; o; o >>= 1) {
        if (threadIdx.x < o) red[threadIdx.x] += red[threadIdx.x + o];
        __syncthreads();
    }
    if (threadIdx.x == 0) rs[r] = red[0];
}

// att[b][j] = max_n x[b][n][j]
__global__ void colmax_kernel(const float* __restrict__ x, float* __restrict__ att)
{
    const int j = blockIdx.x * 256 + threadIdx.x;
    const int b = blockIdx.y;
    const float* p = x + (long)b * 524288 + j;
    float m = -INFINITY;
#pragma unroll 4
    for (int n = 0; n < 512; ++n) m = fmaxf(m, p[(long)n * 1024]);
    att[b * 1024 + j] = m;
}

// =====================================================================
extern "C" void kernel_launch(void* const* d_in, const int* in_sizes, int n_in,
                              void* d_out, int out_size, void* d_ws, size_t ws_size,
                              hipStream_t stream)
{
    const float* xt   = (const float*)d_in[0];
    const float* fc   = (const float*)d_in[1];
    const float* ge   = (const float*)d_in[2];
    const float* sh   = (const float*)d_in[4];   // state_h (2,B,R)
    const float* sc   = (const float*)d_in[5];   // state_c (2,B,R)
    const float* mask = (const float*)d_in[6];   // att_mask (B,N)
    const float* aWih = (const float*)d_in[7];
    const float* aWhh = (const float*)d_in[8];
    const float* aBih = (const float*)d_in[9];
    const float* aBhh = (const float*)d_in[10];
    const float* lWih = (const float*)d_in[11];
    const float* lWhh = (const float*)d_in[12];
    const float* lBih = (const float*)d_in[13];
    const float* lBhh = (const float*)d_in[14];
    const float* e1W  = (const float*)d_in[15];
    const float* e1b  = (const float*)d_in[16];
    const float* e2W  = (const float*)d_in[17];
    const float* e2b  = (const float*)d_in[18];
    const float* W0   = (const float*)d_in[19];
    const float* b0   = (const float*)d_in[20];
    const float* W1   = (const float*)d_in[21];
    const float* b1   = (const float*)d_in[22];
    const float* W2   = (const float*)d_in[23];
    const float* b2   = (const float*)d_in[24];

    float* out = (float*)d_out;
    float* ws  = (float*)d_ws;

    float* e1      = ws + E1_OFF;
    float* e2      = ws + E2_OFF;
    float* Adj     = ws + ADJ_OFF;
    float* tbuf    = e1;   // reuse after Adj is final
    float* xbuf    = e2;   // reuse after Adj is final
    float* gatesT  = ws + GATES1_OFF;
    float* inpT    = ws + INPT_OFF;
    float* h_att   = ws + HATT_OFF;
    float* h_attT  = ws + HATTT_OFF;
    float* v1      = ws + V1_OFF;
    float* v2      = ws + V2_OFF;
    float* part    = ws + PART_OFF;
    float* bmin    = ws + BMIN_OFF;
    float* rowsum  = ws + ROWSUM_OFF;
    float* dv      = ws + DVEC_OFF;
    float* rs      = ws + RS_OFF;
    float* pw0     = ws + PW0_OFF;
    float* attf    = ws + ATTF_OFF;
    float* inp2T   = ws + INP2T_OFF;
    float* gates2T = ws + GATES2_OFF;

    // ---- attention LSTM ----
    pack_inpT1<<<1024, 256, 0, stream>>>(xt, fc, sh, inpT);
    smallM_NT<<<1024, 256, 0, stream>>>(inpT, aWih, 3072, 3072, aWhh, 1024, 1024,
                                        aBih, aBhh, gatesT, 4096, 64, 1);
    lstm_pointwise<<<256, 256, 0, stream>>>(gatesT, sc, h_att, h_attT,
                                            out + BR, out + 3 * BR);

    // ---- e1/e2 bias vectors from h_att ----
    smallM_NT<<<256, 256, 0, stream>>>(h_attT, e1W + 1024, 1024, 2048,
                                       nullptr, 0, 0, nullptr, nullptr, v1, 1024, 1, 1024);
    smallM_NT<<<256, 256, 0, stream>>>(h_attT, e2W + 1024, 1024, 2048,
                                       nullptr, 0, 0, nullptr, nullptr, v2, 1024, 1, 1024);

    // ---- e1, e2 projections (NT, epi1) ----
    gemm_mfma<true, 1><<<dim3(8, 256, 1), 256, 0, stream>>>(
        ge, e1W, e1, 32768, 1024, 1024, 1024, 2048, 1024, 0, 0, 0, v1, e1b, nullptr, mask);
    gemm_mfma<true, 1><<<dim3(8, 256, 1), 256, 0, stream>>>(
        ge, e2W, e2, 32768, 1024, 1024, 1024, 2048, 1024, 0, 0, 0, v2, e2b, nullptr, mask);

    // ---- Adj = e1 @ e2^T (batched NT) ----
    gemm_mfma<true, 0><<<dim3(4, 4, 64), 256, 0, stream>>>(
        e1, e2, Adj, 512, 512, 1024, 1024, 1024, 512,
        524288, 524288, 262144, nullptr, nullptr, nullptr, nullptr);

    // ---- min / top-k / normalization ----
    min_partial<<<dim3(16, 64), 256, 0, stream>>>(Adj, part);
    min_final<<<1, 64, 0, stream>>>(part, bmin);
    topk_rows<<<8192, 256, 0, stream>>>(Adj, bmin, mask, rowsum);
    dvec_kernel<<<128, 256, 0, stream>>>(rowsum, dv);
    adj_norm<<<32768, 256, 0, stream>>>(Adj, dv, mask, rs);

    // ---- GCN layer 0 (rank-1 trick for prev_h part) ----
    smallM_NN<<<256, 256, 0, stream>>>(sh + BR, 1024, W0 + 1024 * 1024, 1024, 1024, pw0, 1024);
    gemm_mfma<false, 0><<<dim3(8, 4, 64), 256, 0, stream>>>(
        Adj, ge, tbuf, 512, 1024, 512, 512, 1024, 1024,
        262144, 524288, 524288, nullptr, nullptr, nullptr, nullptr);
    gemm_mfma<false, 2><<<dim3(8, 256, 1), 256, 0, stream>>>(
        tbuf, W0, xbuf, 32768, 1024, 1024, 1024, 1024, 1024, 0, 0, 0, pw0, b0, rs, mask);

    // ---- GCN layer 1 ----
    gemm_mfma<false, 0><<<dim3(8, 4, 64), 256, 0, stream>>>(
        Adj, xbuf, tbuf, 512, 1024, 512, 512, 1024, 1024,
        262144, 524288, 524288, nullptr, nullptr, nullptr, nullptr);
    gemm_mfma<false, 3><<<dim3(8, 256, 1), 256, 0, stream>>>(
        tbuf, W1, xbuf, 32768, 1024, 1024, 1024, 1024, 1024, 0, 0, 0, nullptr, b1, nullptr, mask);

    // ---- GCN layer 2 ----
    gemm_mfma<false, 0><<<dim3(8, 4, 64), 256, 0, stream>>>(
        Adj, xbuf, tbuf, 512, 1024, 512, 512, 1024, 1024,
        262144, 524288, 524288, nullptr, nullptr, nullptr, nullptr);
    gemm_mfma<false, 3><<<dim3(8, 256, 1), 256, 0, stream>>>(
        tbuf, W2, xbuf, 32768, 1024, 1024, 1024, 1024, 1024, 0, 0, 0, nullptr, b2, nullptr, mask);

    // ---- column max over N ----
    colmax_kernel<<<dim3(4, 64), 256, 0, stream>>>(xbuf, attf);

    // ---- language LSTM ----
    pack_inp2T<<<768, 256, 0, stream>>>(attf, h_att, sh, inp2T);
    smallM_NT<<<1024, 256, 0, stream>>>(inp2T, lWih, 2048, 2048, lWhh, 1024, 1024,
                                        lBih, lBhh, gates2T, 4096, 64, 1);
    lstm_pointwise<<<256, 256, 0, stream>>>(gates2T, sc + BR, out, nullptr,
                                            out + 2 * BR, out + 4 * BR);
    (void)in_sizes; (void)n_in; (void)out_size; (void)ws_size;
}